// Round 3
// baseline (114.551 us; speedup 1.0000x reference)
//
#include <hip/hip_runtime.h>
#include <hip/hip_bf16.h>
#include <cstdint>

#define DI __device__ __forceinline__

typedef __attribute__((ext_vector_type(8))) short short8;
typedef __attribute__((ext_vector_type(4))) float f32x4;

// ---------- bf16 helpers (RNE) ----------
DI float bflo(uint32_t u) { return __builtin_bit_cast(float, (uint32_t)(u << 16)); }
DI float bfhi(uint32_t u) { return __builtin_bit_cast(float, (uint32_t)(u & 0xffff0000u)); }
DI float bf2f(uint16_t u) { return __builtin_bit_cast(float, (uint32_t)((uint32_t)u << 16)); }
DI uint16_t f2bf(float f) {
    uint32_t x = __builtin_bit_cast(uint32_t, f);
    x += 0x7fffu + ((x >> 16) & 1u);
    return (uint16_t)(x >> 16);
}
DI uint32_t pk2bf(float a, float b) {
    return (uint32_t)f2bf(a) | ((uint32_t)f2bf(b) << 16);
}

// ---------- problem constants ----------
constexpr int BATCH = 8, HH_IMG = 56, WW_IMG = 56, C = 192;
constexpr int HEADS = 6, HD = 32, NA = 486;
constexpr int MROWS = BATCH * HH_IMG * WW_IMG;        // 25088
constexpr int KK = 192;                               // shared K of all GEMMs

// =======================================================================
// Big-N MFMA GEMM: block = 128 rows x (full K=192 staged once), then loops
// n-tiles of 64 with double-buffered B. Two output destinations supported
// (tiles < split -> out0/W0, else out1/W1). A fp32 or bf16.
// LDS: A 128x384B swizzled (49152B) reused as 2x 64x384B B buffers.
// 256 thr = 4 waves (2x2); wave owns 64x32; A-frags live in registers.
// =======================================================================
template <bool A_BF16, bool O0_BF16>
__global__ __launch_bounds__(256) void gemm_bigN(
    const void* __restrict__ Ap,
    const float* __restrict__ W0, int N0, void* __restrict__ out0,
    const float* __restrict__ bias0,
    const float* __restrict__ W1, int N1, uint16_t* __restrict__ out1,
    const float* __restrict__ bias1,
    int nt, int split) {
    __shared__ __align__(16) uint8_t sm[49152];
    const int t  = threadIdx.x;
    const int m0 = blockIdx.x * 128;
    const int l  = t & 63, wid = t >> 6;
    const int wr = wid >> 1, wc = wid & 1;
    const int lr = l & 15, lg = l >> 4;

    // ---- stage A: 128 rows x 192 k, bf16, row stride 384B, XOR swizzle ----
    if (A_BF16) {
        const uint16_t* A = (const uint16_t*)Ap;
#pragma unroll
        for (int i = 0; i < 12; ++i) {
            const int f = t + i * 256;             // 16B-slot index (3072 total)
            const int m = f / 24, cb = (f % 24) * 16;
            const uint4 val = *(const uint4*)(A + (size_t)(m0 + m) * KK + (cb >> 1));
            *(uint4*)(sm + m * 384 + (cb ^ ((m & 7) << 4))) = val;
        }
    } else {
        const float* A = (const float*)Ap;
#pragma unroll
        for (int i = 0; i < 12; ++i) {
            const int f = t + i * 256;
            const int m = f / 24, cb = (f % 24) * 16;
            const int k = cb >> 1;
            const float4 v0 = *(const float4*)(A + (size_t)(m0 + m) * KK + k);
            const float4 v1 = *(const float4*)(A + (size_t)(m0 + m) * KK + k + 4);
            uint4 o;
            o.x = pk2bf(v0.x, v0.y); o.y = pk2bf(v0.z, v0.w);
            o.z = pk2bf(v1.x, v1.y); o.w = pk2bf(v1.z, v1.w);
            *(uint4*)(sm + m * 384 + (cb ^ ((m & 7) << 4))) = o;
        }
    }
    __syncthreads();

    // ---- A fragments -> registers (24 short8/wave) ----
    short8 aR[6][4];
#pragma unroll
    for (int ks = 0; ks < 6; ++ks)
#pragma unroll
        for (int mr = 0; mr < 4; ++mr) {
            const int row = wr * 64 + mr * 16 + lr;
            aR[ks][mr] = *(const short8*)(sm + row * 384 +
                          ((ks * 64 + lg * 16) ^ ((row & 7) << 4)));
        }
    __syncthreads();   // all A-frag reads done before B staging reuses LDS

    // ---- B staging (thread owns col bn, 48 k-rows) ----
    const int bn = t & 63, kq = t >> 6;
    auto stageB = [&](int ti) {
        const bool to0  = ti < split;
        const float* Ws = to0 ? W0 : W1;
        const int ncols = to0 ? N0 : N1;
        const int gn    = ti * 64 - (to0 ? 0 : N0) + bn;
        const bool valid = gn < ncols;
        uint8_t* buf = sm + (ti & 1) * 24576 + bn * 384;
        const int sw = (bn & 7) << 4;
        const float* Wf = Ws + (size_t)(kq * 48) * ncols + gn;
#pragma unroll
        for (int e16 = 0; e16 < 6; ++e16) {
            uint32_t d[4];
#pragma unroll
            for (int p = 0; p < 4; ++p) {
                const int e = e16 * 4 + p;
                const float f0 = valid ? Wf[(size_t)(2 * e) * ncols]     : 0.f;
                const float f1 = valid ? Wf[(size_t)(2 * e + 1) * ncols] : 0.f;
                d[p] = pk2bf(f0, f1);
            }
            *(uint4*)(buf + ((kq * 96 + e16 * 16) ^ sw)) = make_uint4(d[0], d[1], d[2], d[3]);
        }
    };

    stageB(0);
    __syncthreads();

    for (int ti = 0; ti < nt; ++ti) {
        if (ti + 1 < nt) stageB(ti + 1);      // fills buf[(ti+1)&1]

        const uint8_t* buf = sm + (ti & 1) * 24576;
        f32x4 acc[4][2];
#pragma unroll
        for (int mr = 0; mr < 4; ++mr) {
            acc[mr][0] = f32x4{0.f, 0.f, 0.f, 0.f};
            acc[mr][1] = f32x4{0.f, 0.f, 0.f, 0.f};
        }
#pragma unroll
        for (int ks = 0; ks < 6; ++ks) {
            const int cb = ks * 64 + lg * 16;
            const int rn0 = wc * 32 + lr, rn1 = rn0 + 16;
            const short8 b0 = *(const short8*)(buf + rn0 * 384 + (cb ^ ((rn0 & 7) << 4)));
            const short8 b1 = *(const short8*)(buf + rn1 * 384 + (cb ^ ((rn1 & 7) << 4)));
#pragma unroll
            for (int mr = 0; mr < 4; ++mr) {
                acc[mr][0] = __builtin_amdgcn_mfma_f32_16x16x32_bf16(aR[ks][mr], b0, acc[mr][0], 0, 0, 0);
                acc[mr][1] = __builtin_amdgcn_mfma_f32_16x16x32_bf16(aR[ks][mr], b1, acc[mr][1], 0, 0, 0);
            }
        }

        // ---- epilogue for this tile: D col=lane&15, row=4*(lane>>4)+reg ----
        const bool to0   = ti < split;
        const int  ncols = to0 ? N0 : N1;
        const int  bcol  = ti * 64 - (to0 ? 0 : N0);
        const float* bias = to0 ? bias0 : bias1;
#pragma unroll
        for (int nr = 0; nr < 2; ++nr) {
            const int col = bcol + wc * 32 + nr * 16 + lr;
            if (col < ncols) {
                const float bv = bias ? bias[col] : 0.f;
#pragma unroll
                for (int mr = 0; mr < 4; ++mr) {
                    const size_t rowb = (size_t)(m0 + wr * 64 + mr * 16 + lg * 4);
#pragma unroll
                    for (int j = 0; j < 4; ++j) {
                        const float val = acc[mr][nr][j] + bv;
                        if (to0) {
                            if (O0_BF16) ((uint16_t*)out0)[(rowb + j) * ncols + col] = f2bf(val);
                            else         ((float*)out0)[(rowb + j) * ncols + col]    = val;
                        } else {
                            out1[(rowb + j) * ncols + col] = f2bf(val);
                        }
                    }
                }
            }
        }
        __syncthreads();   // buf[(ti+1)&1] staged AND buf[ti&1] consumed
    }
}

// =======================================================================
// Fused softmax + attention + fold, 25-offset reassociated gather:
//   y[P] = sum_{dy,dx in [-2,2]} c[dy][dx] * v[P+d],
//   c[d] = sum_{(k,q): q-k=d} softmax_q(scale*alog[P-k+1][n][k][:])[q]
// LDS reads drop 81 -> 25 vectors; softmax runs before __syncthreads()
// to hide halo staging latency.
// =======================================================================
constexpr int TH = 4, TW = 8;
constexpr int HALO_W = TW + 4;                   // 12 (halo H = 8)
constexpr int VSTR = C + 8;                      // 200 bf16

__global__ __launch_bounds__(192) void attn_fold25(const uint16_t* __restrict__ v,
                                                   const uint16_t* __restrict__ alog,
                                                   uint16_t* __restrict__ ypre) {
    __shared__ uint16_t vl[96][VSTR];            // 38.4 KB
    const int b   = blockIdx.z;
    const int ty0 = blockIdx.y * TH, tx0 = blockIdx.x * TW;
    const int t   = threadIdx.x;

    // ---- stage v halo (8x12 px, zero-pad OOB) ----
#pragma unroll
    for (int it = 0; it < 12; ++it) {
        const int f  = t + it * 192;             // 96 px * 24 slots
        const int px = f / 24, c8 = (f % 24) * 8;
        const int hy = px / HALO_W, hx = px % HALO_W;
        const int y = ty0 + hy - 2, x = tx0 + hx - 2;
        uint4 val = make_uint4(0u, 0u, 0u, 0u);
        if ((unsigned)y < HH_IMG && (unsigned)x < WW_IMG)
            val = *(const uint4*)&v[(((size_t)b * HH_IMG + y) * WW_IMG + x) * C + c8];
        *(uint4*)&vl[px][c8] = val;
    }

    const int n   = t % HEADS, pxl = t / HEADS;
    const int py  = pxl / TW, px_ = pxl % TW;
    const int Py  = ty0 + py, Px = tx0 + px_;
    const float scale = 0.17677669529663687f;    // 32^-0.5

    // ---- build 25 fold coefficients (no LDS needed -> overlaps staging) ----
    float cw[5][5] = {};
#pragma unroll
    for (int i = 0; i < 3; ++i)
#pragma unroll
        for (int j = 0; j < 3; ++j) {
            const int sy = Py - i + 1, sx = Px - j + 1;
            if ((unsigned)sy < HH_IMG && (unsigned)sx < WW_IMG) {
                const uint16_t* ap = alog + (((size_t)b * HH_IMG + sy) * WW_IMG + sx) * NA
                                   + n * 81 + (i * 3 + j) * 9;
                float L[9], mx = -1e30f;
#pragma unroll
                for (int q = 0; q < 9; ++q) { L[q] = bf2f(ap[q]) * scale; mx = fmaxf(mx, L[q]); }
                float w[9], s = 0.f;
#pragma unroll
                for (int q = 0; q < 9; ++q) { w[q] = __expf(L[q] - mx); s += w[q]; }
                const float inv = 1.f / s;
#pragma unroll
                for (int qi = 0; qi < 3; ++qi)
#pragma unroll
                    for (int qj = 0; qj < 3; ++qj)
                        cw[qi - i + 2][qj - j + 2] += w[qi * 3 + qj] * inv;
            }
        }
    __syncthreads();

    // ---- 25-offset gather over 32 channels ----
    float acc[HD] = {};
#pragma unroll
    for (int dy = 0; dy < 5; ++dy)
#pragma unroll
        for (int dx = 0; dx < 5; ++dx) {
            const float wq = cw[dy][dx];
            const uint16_t* vp = &vl[(py + dy) * HALO_W + (px_ + dx)][n * HD];
#pragma unroll
            for (int v8 = 0; v8 < 4; ++v8) {
                const uint4 raw = *(const uint4*)&vp[v8 * 8];
                const uint32_t r0 = raw.x, r1 = raw.y, r2 = raw.z, r3 = raw.w;
                acc[v8*8+0] = fmaf(wq, bflo(r0), acc[v8*8+0]);
                acc[v8*8+1] = fmaf(wq, bfhi(r0), acc[v8*8+1]);
                acc[v8*8+2] = fmaf(wq, bflo(r1), acc[v8*8+2]);
                acc[v8*8+3] = fmaf(wq, bfhi(r1), acc[v8*8+3]);
                acc[v8*8+4] = fmaf(wq, bflo(r2), acc[v8*8+4]);
                acc[v8*8+5] = fmaf(wq, bfhi(r2), acc[v8*8+5]);
                acc[v8*8+6] = fmaf(wq, bflo(r3), acc[v8*8+6]);
                acc[v8*8+7] = fmaf(wq, bfhi(r3), acc[v8*8+7]);
            }
        }

    uint16_t* op = ypre + (((size_t)b * HH_IMG + Py) * WW_IMG + Px) * C + n * HD;
#pragma unroll
    for (int d = 0; d < HD; d += 2)
        *(uint32_t*)&op[d] = pk2bf(acc[d], acc[d + 1]);
}

// =======================================================================
extern "C" void kernel_launch(void* const* d_in, const int* in_sizes, int n_in,
                              void* d_out, int out_size, void* d_ws, size_t ws_size,
                              hipStream_t stream) {
    const float* x  = (const float*)d_in[0];
    const float* Wv = (const float*)d_in[1];
    const float* Wa = (const float*)d_in[2];
    const float* ba = (const float*)d_in[3];
    const float* Wp = (const float*)d_in[4];
    const float* bp = (const float*)d_in[5];
    float* out = (float*)d_out;

    // workspace (bf16): v[25088*192] | alog[25088*486] | ypre[25088*192]
    uint16_t* v    = (uint16_t*)d_ws;
    uint16_t* alog = v + (size_t)MROWS * C;
    uint16_t* ypre = alog + (size_t)MROWS * NA;

    // fused projections: v = x@Wv (tiles 0-2), alog = x@Wa + ba (tiles 3-10)
    gemm_bigN<false, true><<<MROWS / 128, 256, 0, stream>>>(
        x, Wv, C, v, nullptr, Wa, NA, alog, ba, 11, 3);
    // softmax + attn + fold -> ypre
    attn_fold25<<<dim3(WW_IMG / TW, HH_IMG / TH, BATCH), dim3(192), 0, stream>>>(
        v, alog, ypre);
    // out = ypre @ Wp + bp
    gemm_bigN<true, false><<<MROWS / 128, 256, 0, stream>>>(
        ypre, Wp, C, out, bp, nullptr, 0, nullptr, nullptr, 3, 3);
}

// Round 4
// 68.947 us; speedup vs baseline: 1.6614x; 1.6614x over previous
//
#include <hip/hip_runtime.h>
#include <hip/hip_bf16.h>
#include <cstdint>

#define DI __device__ __forceinline__

typedef __attribute__((ext_vector_type(8))) short short8;
typedef __attribute__((ext_vector_type(4))) float f32x4;

// ---------- bf16 helpers (RNE) ----------
DI float bflo(uint32_t u) { return __builtin_bit_cast(float, (uint32_t)(u << 16)); }
DI float bfhi(uint32_t u) { return __builtin_bit_cast(float, (uint32_t)(u & 0xffff0000u)); }
DI float bf2f(uint16_t u) { return __builtin_bit_cast(float, (uint32_t)((uint32_t)u << 16)); }
DI uint16_t f2bf(float f) {
    uint32_t x = __builtin_bit_cast(uint32_t, f);
    x += 0x7fffu + ((x >> 16) & 1u);
    return (uint16_t)(x >> 16);
}
DI uint32_t pk2bf(float a, float b) {
    return (uint32_t)f2bf(a) | ((uint32_t)f2bf(b) << 16);
}

// m204 bijective XCD-chunk swizzle: consecutive wgid -> same XCD chunk.
DI int xcd_swizzle(int orig, int nwg) {
    const int q = nwg >> 3, r = nwg & 7;
    const int x = orig & 7, i = orig >> 3;
    return (x < r ? x * (q + 1) : r * (q + 1) + (x - r) * q) + i;
}

// ---------- problem constants ----------
constexpr int BATCH = 8, HH_IMG = 56, WW_IMG = 56, C = 192;
constexpr int HEADS = 6, HD = 32, NA = 486;
constexpr int MROWS = BATCH * HH_IMG * WW_IMG;        // 25088
constexpr int KK = 192;

// =======================================================================
// One block = one 128x64 output tile, FULL K=192 staged once (no K loop).
// A (fp32 or bf16) -> LDS swizzled -> 24 short8 regs/wave; B (fp32,
// row-major [k][n]) -> LDS (reuses A region); 48 MFMA back-to-back.
// Grid = (M/128) * NT, linearized with XCD-chunk swizzle so the NT blocks
// sharing an A-panel hit the same XCD's L2. Dual destination (ti<SPLIT ->
// W0/out0 else W1/out1). 256 thr = 4 waves (2x2), wave owns 64x32.
// =======================================================================
template <bool A_BF16, bool O0_BF16, int NT, int SPLIT>
__global__ __launch_bounds__(256) void gemm_tile(
    const void* __restrict__ Ap,
    const float* __restrict__ W0, int N0, void* __restrict__ out0,
    const float* __restrict__ bias0,
    const float* __restrict__ W1, int N1, uint16_t* __restrict__ out1,
    const float* __restrict__ bias1) {
    __shared__ __align__(16) uint8_t sm[49152];      // A 48KB, B reuses first 24KB
    const int t    = threadIdx.x;
    const int wgid = xcd_swizzle(blockIdx.x, gridDim.x);
    const int mg   = wgid / NT, ti = wgid - mg * NT; // NT compile-time -> magic mul
    const int m0   = mg * 128;
    const int l    = t & 63, wid = t >> 6;
    const int wr   = wid >> 1, wc = wid & 1;
    const int lr   = l & 15, lg = l >> 4;

    // ---- stage A: 128 rows x 192 k, bf16, row stride 384B, XOR swizzle ----
    if (A_BF16) {
        const uint16_t* A = (const uint16_t*)Ap;
#pragma unroll
        for (int i = 0; i < 12; ++i) {
            const int f = t + i * 256;               // 3072 16B slots
            const int m = f / 24, cb = (f % 24) * 16;
            const uint4 val = *(const uint4*)(A + (size_t)(m0 + m) * KK + (cb >> 1));
            *(uint4*)(sm + m * 384 + (cb ^ ((m & 7) << 4))) = val;
        }
    } else {
        const float* A = (const float*)Ap;
#pragma unroll
        for (int i = 0; i < 12; ++i) {
            const int f = t + i * 256;
            const int m = f / 24, cb = (f % 24) * 16;
            const int k = cb >> 1;
            const float4 v0 = *(const float4*)(A + (size_t)(m0 + m) * KK + k);
            const float4 v1 = *(const float4*)(A + (size_t)(m0 + m) * KK + k + 4);
            uint4 o;
            o.x = pk2bf(v0.x, v0.y); o.y = pk2bf(v0.z, v0.w);
            o.z = pk2bf(v1.x, v1.y); o.w = pk2bf(v1.z, v1.w);
            *(uint4*)(sm + m * 384 + (cb ^ ((m & 7) << 4))) = o;
        }
    }
    __syncthreads();

    // ---- A fragments -> registers (24 short8/wave) ----
    short8 aR[6][4];
#pragma unroll
    for (int ks = 0; ks < 6; ++ks)
#pragma unroll
        for (int mr = 0; mr < 4; ++mr) {
            const int row = wr * 64 + mr * 16 + lr;
            aR[ks][mr] = *(const short8*)(sm + row * 384 +
                          ((ks * 64 + lg * 16) ^ ((row & 7) << 4)));
        }
    __syncthreads();   // A LDS dead -> B may overwrite

    // ---- stage B: 64 cols x 192 k into first 24KB (thread owns col bn) ----
    const bool  to0   = ti < SPLIT;
    const float* Ws   = to0 ? W0 : W1;
    const int   ncols = to0 ? N0 : N1;
    const int   bcol  = ti * 64 - (to0 ? 0 : N0);
    {
        const int bn = t & 63, kq = t >> 6;          // col, k-quarter (48 rows)
        const int gn = bcol + bn;
        const bool valid = gn < ncols;
        uint8_t* buf = sm + bn * 384;
        const int sw = (bn & 7) << 4;
        const float* Wf = Ws + (size_t)(kq * 48) * ncols + gn;
#pragma unroll
        for (int e16 = 0; e16 < 6; ++e16) {
            uint32_t d[4];
#pragma unroll
            for (int p = 0; p < 4; ++p) {
                const int e = e16 * 4 + p;
                const float f0 = valid ? Wf[(size_t)(2 * e) * ncols]     : 0.f;
                const float f1 = valid ? Wf[(size_t)(2 * e + 1) * ncols] : 0.f;
                d[p] = pk2bf(f0, f1);
            }
            *(uint4*)(buf + ((kq * 96 + e16 * 16) ^ sw)) = make_uint4(d[0], d[1], d[2], d[3]);
        }
    }
    __syncthreads();

    // ---- compute: 48 MFMA, B frags from LDS ----
    f32x4 acc[4][2];
#pragma unroll
    for (int mr = 0; mr < 4; ++mr) {
        acc[mr][0] = f32x4{0.f, 0.f, 0.f, 0.f};
        acc[mr][1] = f32x4{0.f, 0.f, 0.f, 0.f};
    }
#pragma unroll
    for (int ks = 0; ks < 6; ++ks) {
        const int cb  = ks * 64 + lg * 16;
        const int rn0 = wc * 32 + lr, rn1 = rn0 + 16;
        const short8 b0 = *(const short8*)(sm + rn0 * 384 + (cb ^ ((rn0 & 7) << 4)));
        const short8 b1 = *(const short8*)(sm + rn1 * 384 + (cb ^ ((rn1 & 7) << 4)));
#pragma unroll
        for (int mr = 0; mr < 4; ++mr) {
            acc[mr][0] = __builtin_amdgcn_mfma_f32_16x16x32_bf16(aR[ks][mr], b0, acc[mr][0], 0, 0, 0);
            acc[mr][1] = __builtin_amdgcn_mfma_f32_16x16x32_bf16(aR[ks][mr], b1, acc[mr][1], 0, 0, 0);
        }
    }

    // ---- epilogue: D col=lane&15, row=4*(lane>>4)+reg ----
    const float* bias = to0 ? bias0 : bias1;
#pragma unroll
    for (int nr = 0; nr < 2; ++nr) {
        const int col = bcol + wc * 32 + nr * 16 + lr;
        if (col < ncols) {
            const float bv = bias ? bias[col] : 0.f;
#pragma unroll
            for (int mr = 0; mr < 4; ++mr) {
                const size_t rowb = (size_t)(m0 + wr * 64 + mr * 16 + lg * 4);
#pragma unroll
                for (int j = 0; j < 4; ++j) {
                    const float val = acc[mr][nr][j] + bv;
                    if (to0) {
                        if (O0_BF16) ((uint16_t*)out0)[(rowb + j) * ncols + col] = f2bf(val);
                        else         ((float*)out0)[(rowb + j) * ncols + col]    = val;
                    } else {
                        out1[(rowb + j) * ncols + col] = f2bf(val);
                    }
                }
            }
        }
    }
}

// =======================================================================
// Fused softmax + attention + fold, 25-offset reassociated gather.
// (unchanged from round 3)
// =======================================================================
constexpr int TH = 4, TW = 8;
constexpr int HALO_W = TW + 4;                   // 12 (halo H = 8)
constexpr int VSTR = C + 8;                      // 200 bf16

__global__ __launch_bounds__(192) void attn_fold25(const uint16_t* __restrict__ v,
                                                   const uint16_t* __restrict__ alog,
                                                   uint16_t* __restrict__ ypre) {
    __shared__ uint16_t vl[96][VSTR];            // 38.4 KB
    const int b   = blockIdx.z;
    const int ty0 = blockIdx.y * TH, tx0 = blockIdx.x * TW;
    const int t   = threadIdx.x;

#pragma unroll
    for (int it = 0; it < 12; ++it) {
        const int f  = t + it * 192;             // 96 px * 24 slots
        const int px = f / 24, c8 = (f % 24) * 8;
        const int hy = px / HALO_W, hx = px % HALO_W;
        const int y = ty0 + hy - 2, x = tx0 + hx - 2;
        uint4 val = make_uint4(0u, 0u, 0u, 0u);
        if ((unsigned)y < HH_IMG && (unsigned)x < WW_IMG)
            val = *(const uint4*)&v[(((size_t)b * HH_IMG + y) * WW_IMG + x) * C + c8];
        *(uint4*)&vl[px][c8] = val;
    }

    const int n   = t % HEADS, pxl = t / HEADS;
    const int py  = pxl / TW, px_ = pxl % TW;
    const int Py  = ty0 + py, Px = tx0 + px_;
    const float scale = 0.17677669529663687f;    // 32^-0.5

    float cw[5][5] = {};
#pragma unroll
    for (int i = 0; i < 3; ++i)
#pragma unroll
        for (int j = 0; j < 3; ++j) {
            const int sy = Py - i + 1, sx = Px - j + 1;
            if ((unsigned)sy < HH_IMG && (unsigned)sx < WW_IMG) {
                const uint16_t* ap = alog + (((size_t)b * HH_IMG + sy) * WW_IMG + sx) * NA
                                   + n * 81 + (i * 3 + j) * 9;
                float L[9], mx = -1e30f;
#pragma unroll
                for (int q = 0; q < 9; ++q) { L[q] = bf2f(ap[q]) * scale; mx = fmaxf(mx, L[q]); }
                float w[9], s = 0.f;
#pragma unroll
                for (int q = 0; q < 9; ++q) { w[q] = __expf(L[q] - mx); s += w[q]; }
                const float inv = 1.f / s;
#pragma unroll
                for (int qi = 0; qi < 3; ++qi)
#pragma unroll
                    for (int qj = 0; qj < 3; ++qj)
                        cw[qi - i + 2][qj - j + 2] += w[qi * 3 + qj] * inv;
            }
        }
    __syncthreads();

    float acc[HD] = {};
#pragma unroll
    for (int dy = 0; dy < 5; ++dy)
#pragma unroll
        for (int dx = 0; dx < 5; ++dx) {
            const float wq = cw[dy][dx];
            const uint16_t* vp = &vl[(py + dy) * HALO_W + (px_ + dx)][n * HD];
#pragma unroll
            for (int v8 = 0; v8 < 4; ++v8) {
                const uint4 raw = *(const uint4*)&vp[v8 * 8];
                const uint32_t r0 = raw.x, r1 = raw.y, r2 = raw.z, r3 = raw.w;
                acc[v8*8+0] = fmaf(wq, bflo(r0), acc[v8*8+0]);
                acc[v8*8+1] = fmaf(wq, bfhi(r0), acc[v8*8+1]);
                acc[v8*8+2] = fmaf(wq, bflo(r1), acc[v8*8+2]);
                acc[v8*8+3] = fmaf(wq, bfhi(r1), acc[v8*8+3]);
                acc[v8*8+4] = fmaf(wq, bflo(r2), acc[v8*8+4]);
                acc[v8*8+5] = fmaf(wq, bfhi(r2), acc[v8*8+5]);
                acc[v8*8+6] = fmaf(wq, bflo(r3), acc[v8*8+6]);
                acc[v8*8+7] = fmaf(wq, bfhi(r3), acc[v8*8+7]);
            }
        }

    uint16_t* op = ypre + (((size_t)b * HH_IMG + Py) * WW_IMG + Px) * C + n * HD;
#pragma unroll
    for (int d = 0; d < HD; d += 2)
        *(uint32_t*)&op[d] = pk2bf(acc[d], acc[d + 1]);
}

// =======================================================================
extern "C" void kernel_launch(void* const* d_in, const int* in_sizes, int n_in,
                              void* d_out, int out_size, void* d_ws, size_t ws_size,
                              hipStream_t stream) {
    const float* x  = (const float*)d_in[0];
    const float* Wv = (const float*)d_in[1];
    const float* Wa = (const float*)d_in[2];
    const float* ba = (const float*)d_in[3];
    const float* Wp = (const float*)d_in[4];
    const float* bp = (const float*)d_in[5];
    float* out = (float*)d_out;

    // workspace (bf16): v[25088*192] | alog[25088*486] | ypre[25088*192]
    uint16_t* v    = (uint16_t*)d_ws;
    uint16_t* alog = v + (size_t)MROWS * C;
    uint16_t* ypre = alog + (size_t)MROWS * NA;

    // fused projections: tiles 0-2 -> v = x@Wv, tiles 3-10 -> alog = x@Wa+ba
    gemm_tile<false, true, 11, 3><<<(MROWS / 128) * 11, 256, 0, stream>>>(
        x, Wv, C, v, nullptr, Wa, NA, alog, ba);
    // softmax + attn + fold -> ypre
    attn_fold25<<<dim3(WW_IMG / TW, HH_IMG / TH, BATCH), dim3(192), 0, stream>>>(
        v, alog, ypre);
    // out = ypre @ Wp + bp
    gemm_tile<true, false, 3, 3><<<(MROWS / 128) * 3, 256, 0, stream>>>(
        ypre, Wp, C, out, bp, nullptr, 0, nullptr, nullptr);
}

// Round 5
// 67.776 us; speedup vs baseline: 1.6901x; 1.0173x over previous
//
#include <hip/hip_runtime.h>
#include <hip/hip_bf16.h>
#include <cstdint>

#define DI __device__ __forceinline__

typedef __attribute__((ext_vector_type(8))) short short8;
typedef __attribute__((ext_vector_type(4))) float f32x4;

// ---------- bf16 helpers ----------
DI float bflo(uint32_t u) { return __builtin_bit_cast(float, (uint32_t)(u << 16)); }
DI float bfhi(uint32_t u) { return __builtin_bit_cast(float, (uint32_t)(u & 0xffff0000u)); }
DI float bf2f(uint16_t u) { return __builtin_bit_cast(float, (uint32_t)((uint32_t)u << 16)); }
// HW packed cvt: D.lo = bf16(lo), D.hi = bf16(hi), RNE. (no builtin on gfx950)
DI uint32_t cvtpk(float lo, float hi) {
    uint32_t r;
    asm("v_cvt_pk_bf16_f32 %0, %1, %2" : "=v"(r) : "v"(lo), "v"(hi));
    return r;
}

// async global->LDS, 16B per lane (dest = wave-uniform base + lane*16)
DI void gload16(const void* g, void* s) {
    __builtin_amdgcn_global_load_lds(
        (const __attribute__((address_space(1))) uint32_t*)g,
        (__attribute__((address_space(3))) uint32_t*)s, 16, 0, 0);
}

// m204 bijective XCD-chunk swizzle
DI int xcd_swizzle(int orig, int nwg) {
    const int q = nwg >> 3, r = nwg & 7;
    const int x = orig & 7, i = orig >> 3;
    return (x < r ? x * (q + 1) : r * (q + 1) + (x - r) * q) + i;
}

// ---------- problem constants ----------
constexpr int BATCH = 8, HH_IMG = 56, WW_IMG = 56, C = 192;
constexpr int HEADS = 6, HD = 32, NA = 486;
constexpr int MROWS = BATCH * HH_IMG * WW_IMG;        // 25088
constexpr int KK = 192;
constexpr int TILE_B = 49152;                         // 128 cols x 384B

// =======================================================================
// Weight prep: bf16 + transpose + XOR-swizzle + column pair-interleave.
// Tile = 128 unified cols x 192 k (bf16, 384B/row, row = physical col).
// Physical row p within a 32-col group holds logical col 2*(p&15)+((p>>4)&1)
// so MFMA frag pairs (nr even/odd) give ADJACENT memory cols -> packed
// epilogue stores. Tiles 0..5: unified proj cols [Wv 0..191 | Wa 192..677 |
// zero]; tiles 6..7: [Wp 0..191 | zero].
// =======================================================================
__global__ __launch_bounds__(256) void prep_wt(const float* __restrict__ Wv,
                                               const float* __restrict__ Wa,
                                               const float* __restrict__ Wp,
                                               uint8_t* __restrict__ WT) {
    const int tid = blockIdx.x * 256 + threadIdx.x;   // 8*128*24 = 24576
    const int s = tid % 24, rem = tid / 24;
    const int p = rem & 127, tile = rem >> 7;
    const int lc = (p >> 5) * 32 + 2 * (p & 15) + ((p >> 4) & 1);
    const int u  = (tile < 6 ? tile : tile - 6) * 128 + lc;

    const float* src = nullptr; int nc = 0, col = 0;
    if (tile < 6) {
        if (u < 192)      { src = Wv; nc = 192; col = u; }
        else if (u < 678) { src = Wa; nc = NA;  col = u - 192; }
    } else {
        if (u < 192)      { src = Wp; nc = 192; col = u; }
    }

    const int k0 = s * 8;
    uint32_t d[4];
#pragma unroll
    for (int e = 0; e < 4; ++e) {
        const float f0 = src ? src[(size_t)(k0 + 2 * e) * nc + col]     : 0.f;
        const float f1 = src ? src[(size_t)(k0 + 2 * e + 1) * nc + col] : 0.f;
        d[e] = cvtpk(f0, f1);
    }
    const int sb = (s * 16) ^ ((p & 7) << 4);
    *(uint4*)(WT + (size_t)tile * TILE_B + p * 384 + sb) =
        make_uint4(d[0], d[1], d[2], d[3]);
}

// =======================================================================
// 128x128 MFMA GEMM, full K=192 staged once. 256 thr = 4 waves (2x2),
// wave = 64x64 out = acc[4][4]. A: fp32 (cvt_pk staged) or bf16
// PRE-SWIZZLED (pure global_load_lds). B: pre-swizzled bf16 tile,
// 12x global_load_lds into the (dead) A region. Unified-column output:
// OUT_DUAL -> v (cols<192, no bias) / alog (+ba); else fp32 out (+bias).
// =======================================================================
template <bool A_BF16, bool OUT_DUAL, int NT>
__global__ __launch_bounds__(256, 2) void gemm128(
    const void* __restrict__ Ap,
    const uint8_t* __restrict__ WT,
    uint16_t* __restrict__ vOut, uint16_t* __restrict__ alogOut,
    const float* __restrict__ bias,
    float* __restrict__ outf) {
    __shared__ __align__(16) uint8_t sm[TILE_B];      // 48KB, A then B
    const int t    = threadIdx.x;
    const int wgid = xcd_swizzle(blockIdx.x, gridDim.x);
    const int mg   = wgid / NT, ti = wgid - mg * NT;
    const int m0   = mg * 128;
    const int l    = t & 63, wid = t >> 6;
    const int wr   = wid >> 1, wc = wid & 1;
    const int lr   = l & 15, lg = l >> 4;

    // ---- stage A (128 rows x 384B, swizzled) ----
    if (A_BF16) {
        // ypre is stored pre-swizzled: straight 48KB copy
        const uint8_t* src = (const uint8_t*)Ap + (size_t)m0 * 384;
#pragma unroll
        for (int i = 0; i < 12; ++i) {
            const int off = wid * 12288 + i * 1024;
            gload16(src + off + l * 16, sm + off);
        }
        __syncthreads();   // gload drains at barrier
    } else {
        const float* A = (const float*)Ap;
#pragma unroll
        for (int i = 0; i < 12; ++i) {
            const int f = t + i * 256;                // 3072 16B slots
            const int m = f / 24, cb = (f % 24) * 16;
            const int k = cb >> 1;
            const float4 v0 = *(const float4*)(A + (size_t)(m0 + m) * KK + k);
            const float4 v1 = *(const float4*)(A + (size_t)(m0 + m) * KK + k + 4);
            uint4 o;
            o.x = cvtpk(v0.x, v0.y); o.y = cvtpk(v0.z, v0.w);
            o.z = cvtpk(v1.x, v1.y); o.w = cvtpk(v1.z, v1.w);
            *(uint4*)(sm + m * 384 + (cb ^ ((m & 7) << 4))) = o;
        }
        __syncthreads();
    }

    // ---- A fragments -> registers (24 short8/wave) ----
    short8 aR[6][4];
#pragma unroll
    for (int ks = 0; ks < 6; ++ks)
#pragma unroll
        for (int mr = 0; mr < 4; ++mr) {
            const int row = wr * 64 + mr * 16 + lr;
            aR[ks][mr] = *(const short8*)(sm + row * 384 +
                          ((ks * 64 + lg * 16) ^ ((row & 7) << 4)));
        }
    __syncthreads();       // all A reads done -> B may overwrite

    // ---- stage B: pre-swizzled tile, pure async copy ----
    {
        const uint8_t* wt = WT + (size_t)ti * TILE_B;
#pragma unroll
        for (int i = 0; i < 12; ++i) {
            const int off = wid * 12288 + i * 1024;
            gload16(wt + off + l * 16, sm + off);
        }
    }
    __syncthreads();       // compiler emits vmcnt(0) before barrier

    // ---- compute: 96 MFMA/wave ----
    f32x4 acc[4][4];
#pragma unroll
    for (int mr = 0; mr < 4; ++mr)
#pragma unroll
        for (int nr = 0; nr < 4; ++nr) acc[mr][nr] = f32x4{0.f, 0.f, 0.f, 0.f};
#pragma unroll
    for (int ks = 0; ks < 6; ++ks) {
        const int cb = ks * 64 + lg * 16;
        short8 b[4];
#pragma unroll
        for (int nr = 0; nr < 4; ++nr) {
            const int rn = wc * 64 + nr * 16 + lr;
            b[nr] = *(const short8*)(sm + rn * 384 + (cb ^ ((rn & 7) << 4)));
        }
#pragma unroll
        for (int mr = 0; mr < 4; ++mr)
#pragma unroll
            for (int nr = 0; nr < 4; ++nr)
                acc[mr][nr] = __builtin_amdgcn_mfma_f32_16x16x32_bf16(
                    aR[ks][mr], b[nr], acc[mr][nr], 0, 0, 0);
    }

    // ---- epilogue: frag pair (2pr,2pr+1) = memory cols (c, c+1) ----
    const int gcol0 = ti * 128 + wc * 64;             // wave-uniform
#pragma unroll
    for (int pr = 0; pr < 2; ++pr) {
        if (OUT_DUAL) {
            const bool isv = gcol0 < 192;
            uint16_t* dst = isv ? vOut : alogOut;
            const int nc  = isv ? 192 : NA;
            const int c   = (isv ? gcol0 : gcol0 - 192) + pr * 32 + 2 * lr;
            if (c < nc) {
                const float be = isv ? 0.f : bias[c];
                const float bo = isv ? 0.f : bias[c + 1];
#pragma unroll
                for (int mr = 0; mr < 4; ++mr) {
                    const size_t rb = (size_t)(m0 + wr * 64 + mr * 16 + lg * 4);
#pragma unroll
                    for (int j = 0; j < 4; ++j)
                        *(uint32_t*)(dst + (rb + j) * nc + c) =
                            cvtpk(acc[mr][2 * pr][j] + be, acc[mr][2 * pr + 1][j] + bo);
                }
            }
        } else {
            const int c = gcol0 + pr * 32 + 2 * lr;
            if (c < 192) {
                const float be = bias[c], bo = bias[c + 1];
#pragma unroll
                for (int mr = 0; mr < 4; ++mr) {
                    const size_t rb = (size_t)(m0 + wr * 64 + mr * 16 + lg * 4);
#pragma unroll
                    for (int j = 0; j < 4; ++j)
                        *(float2*)(outf + (rb + j) * 192 + c) =
                            make_float2(acc[mr][2 * pr][j] + be,
                                        acc[mr][2 * pr + 1][j] + bo);
                }
            }
        }
    }
}

// =======================================================================
// Fused softmax + attention + fold (25-offset gather). Changes vs r4:
// no max-subtraction (logits tiny; exp2 with folded scale*log2e), HW
// cvt_pk stores, and ypre stored PRE-SWIZZLED for the final GEMM's
// global_load_lds A-path.
// =======================================================================
constexpr int TH = 4, TW = 8;
constexpr int HALO_W = TW + 4;                   // 12 (halo H = 8)
constexpr int VSTR = C + 8;                      // 200 bf16

__global__ __launch_bounds__(192) void attn_fold25(const uint16_t* __restrict__ v,
                                                   const uint16_t* __restrict__ alog,
                                                   uint16_t* __restrict__ ypre) {
    __shared__ uint16_t vl[96][VSTR];            // 38.4 KB
    const int b   = blockIdx.z;
    const int ty0 = blockIdx.y * TH, tx0 = blockIdx.x * TW;
    const int t   = threadIdx.x;

#pragma unroll
    for (int it = 0; it < 12; ++it) {
        const int f  = t + it * 192;             // 96 px * 24 slots
        const int px = f / 24, c8 = (f % 24) * 8;
        const int hy = px / HALO_W, hx = px % HALO_W;
        const int y = ty0 + hy - 2, x = tx0 + hx - 2;
        uint4 val = make_uint4(0u, 0u, 0u, 0u);
        if ((unsigned)y < HH_IMG && (unsigned)x < WW_IMG)
            val = *(const uint4*)&v[(((size_t)b * HH_IMG + y) * WW_IMG + x) * C + c8];
        *(uint4*)&vl[px][c8] = val;
    }

    const int n   = t % HEADS, pxl = t / HEADS;
    const int py  = pxl / TW, px_ = pxl % TW;
    const int Py  = ty0 + py, Px = tx0 + px_;
    // scale * log2(e): softmax via exp2, no max subtraction (|logit|<~2)
    const float scl2 = 0.17677669529663687f * 1.4426950408889634f;

    float cw[5][5] = {};
#pragma unroll
    for (int i = 0; i < 3; ++i)
#pragma unroll
        for (int j = 0; j < 3; ++j) {
            const int sy = Py - i + 1, sx = Px - j + 1;
            if ((unsigned)sy < HH_IMG && (unsigned)sx < WW_IMG) {
                const uint16_t* ap = alog + (((size_t)b * HH_IMG + sy) * WW_IMG + sx) * NA
                                   + n * 81 + (i * 3 + j) * 9;
                float w[9], s = 0.f;
#pragma unroll
                for (int q = 0; q < 9; ++q) {
                    w[q] = __builtin_amdgcn_exp2f(bf2f(ap[q]) * scl2);
                    s += w[q];
                }
                const float inv = __builtin_amdgcn_rcpf(s);
#pragma unroll
                for (int qi = 0; qi < 3; ++qi)
#pragma unroll
                    for (int qj = 0; qj < 3; ++qj)
                        cw[qi - i + 2][qj - j + 2] += w[qi * 3 + qj] * inv;
            }
        }
    __syncthreads();

    float acc[HD] = {};
#pragma unroll
    for (int dy = 0; dy < 5; ++dy)
#pragma unroll
        for (int dx = 0; dx < 5; ++dx) {
            const float wq = cw[dy][dx];
            const uint16_t* vp = &vl[(py + dy) * HALO_W + (px_ + dx)][n * HD];
#pragma unroll
            for (int v8 = 0; v8 < 4; ++v8) {
                const uint4 raw = *(const uint4*)&vp[v8 * 8];
                const uint32_t r0 = raw.x, r1 = raw.y, r2 = raw.z, r3 = raw.w;
                acc[v8*8+0] = fmaf(wq, bflo(r0), acc[v8*8+0]);
                acc[v8*8+1] = fmaf(wq, bfhi(r0), acc[v8*8+1]);
                acc[v8*8+2] = fmaf(wq, bflo(r1), acc[v8*8+2]);
                acc[v8*8+3] = fmaf(wq, bfhi(r1), acc[v8*8+3]);
                acc[v8*8+4] = fmaf(wq, bflo(r2), acc[v8*8+4]);
                acc[v8*8+5] = fmaf(wq, bfhi(r2), acc[v8*8+5]);
                acc[v8*8+6] = fmaf(wq, bflo(r3), acc[v8*8+6]);
                acc[v8*8+7] = fmaf(wq, bfhi(r3), acc[v8*8+7]);
            }
        }

    // ---- store ypre PRE-SWIZZLED (byte ^ ((pixel&7)<<4) within 384B row) ----
    const size_t Pidx = ((size_t)b * HH_IMG + Py) * WW_IMG + Px;
    uint8_t* op = (uint8_t*)ypre + Pidx * 384;
    const int key = ((int)Pidx & 7) << 4;
#pragma unroll
    for (int d = 0; d < HD; d += 2)
        *(uint32_t*)(op + ((n * 64 + d * 2) ^ key)) = cvtpk(acc[d], acc[d + 1]);
}

// =======================================================================
extern "C" void kernel_launch(void* const* d_in, const int* in_sizes, int n_in,
                              void* d_out, int out_size, void* d_ws, size_t ws_size,
                              hipStream_t stream) {
    const float* x  = (const float*)d_in[0];
    const float* Wv = (const float*)d_in[1];
    const float* Wa = (const float*)d_in[2];
    const float* ba = (const float*)d_in[3];
    const float* Wp = (const float*)d_in[4];
    const float* bp = (const float*)d_in[5];
    float* out = (float*)d_out;

    // ws: v[25088*192] | alog[25088*486] | ypre[25088*192 pre-swz] | WT 8 tiles
    uint16_t* v    = (uint16_t*)d_ws;
    uint16_t* alog = v + (size_t)MROWS * C;
    uint16_t* ypre = alog + (size_t)MROWS * NA;
    uint8_t*  WT   = (uint8_t*)(ypre + (size_t)MROWS * C);

    // weight prep (bf16 + transpose + swizzle + pair-interleave)
    prep_wt<<<96, 256, 0, stream>>>(Wv, Wa, Wp, WT);
    // fused projections: unified 6 tiles -> v (cols<192) + alog (+ba)
    gemm128<false, true, 6><<<(MROWS / 128) * 6, 256, 0, stream>>>(
        x, WT, v, alog, ba, nullptr);
    // softmax + attn + fold -> ypre (pre-swizzled)
    attn_fold25<<<dim3(WW_IMG / TW, HH_IMG / TH, BATCH), dim3(192), 0, stream>>>(
        v, alog, ypre);
    // out = ypre @ Wp + bp (fp32)
    gemm128<true, false, 2><<<(MROWS / 128) * 2, 256, 0, stream>>>(
        ypre, WT + 6 * (size_t)TILE_B, nullptr, nullptr, bp, out);
}

// Round 6
// 61.642 us; speedup vs baseline: 1.8583x; 1.0995x over previous
//
#include <hip/hip_runtime.h>
#include <hip/hip_bf16.h>
#include <cstdint>

#define DI __device__ __forceinline__

typedef __attribute__((ext_vector_type(8))) short short8;
typedef __attribute__((ext_vector_type(4))) float f32x4;

// ---------- bf16 helpers ----------
DI float bflo(uint32_t u) { return __builtin_bit_cast(float, (uint32_t)(u << 16)); }
DI float bfhi(uint32_t u) { return __builtin_bit_cast(float, (uint32_t)(u & 0xffff0000u)); }
DI float bf2f(uint16_t u) { return __builtin_bit_cast(float, (uint32_t)((uint32_t)u << 16)); }
// HW packed cvt (RNE); no builtin on gfx950
DI uint32_t cvtpk(float lo, float hi) {
    uint32_t r;
    asm("v_cvt_pk_bf16_f32 %0, %1, %2" : "=v"(r) : "v"(lo), "v"(hi));
    return r;
}
// async global->LDS, 16B/lane (dest = wave-uniform base + lane*16)
DI void gload16(const void* g, void* s) {
    __builtin_amdgcn_global_load_lds(
        (const __attribute__((address_space(1))) uint32_t*)g,
        (__attribute__((address_space(3))) uint32_t*)s, 16, 0, 0);
}
// m204 bijective XCD-chunk swizzle
DI int xcd_swizzle(int orig, int nwg) {
    const int q = nwg >> 3, r = nwg & 7;
    const int x = orig & 7, i = orig >> 3;
    return (x < r ? x * (q + 1) : r * (q + 1) + (x - r) * q) + i;
}

// ---------- problem constants ----------
constexpr int BATCH = 8, HH_IMG = 56, WW_IMG = 56, C = 192;
constexpr int HEADS = 6, HD = 32, NA = 486;
constexpr int MROWS = BATCH * HH_IMG * WW_IMG;        // 25088
constexpr int KK = 192;
constexpr int TILE_B  = 49152;                        // B tile: 128 cols x 384B
constexpr int PANEL_B = 49152;                        // A panel: 128 rows x 192k bf16

// =======================================================================
// Fragment-order layout for A operands (per 128-row panel):
//   granule (r16 in 0..7, ks in 0..5, lane l in 0..63) at byte
//   ((r16*6+ks)*64 + l)*16, holding rows r16*16+(l&15), k = ks*32+(l>>4)*8..+8
//   as 4 dwords of bf16 pairs (2e,2e+1). A wave's MFMA A-frag load is then
//   ONE coalesced global_load_dwordx4 (uniform base + l*16).
// =======================================================================

// ---- combined prep: blocks [0,2352): x -> frag-order bf16;
//      blocks [2352,2448): weights -> transposed/swizzled/pair-interleaved ----
__global__ __launch_bounds__(256) void prep_all(const float* __restrict__ x,
                                                const float* __restrict__ Wv,
                                                const float* __restrict__ Wa,
                                                const float* __restrict__ Wp,
                                                uint8_t* __restrict__ xbf,
                                                uint8_t* __restrict__ WT) {
    const int bid = blockIdx.x;
    if (bid < 2352) {
        // x[m][k0..k0+7] fp32 -> 16B bf16 granule in frag order
        const int g = bid * 256 + threadIdx.x;        // 602112 granules
        const int m = g / 24, cc = g % 24;            // row, k-chunk
        const int ks = cc >> 2, lg = cc & 3;
        const float* src = x + (size_t)m * KK + cc * 8;
        const float4 v0 = *(const float4*)src;
        const float4 v1 = *(const float4*)(src + 4);
        uint4 o;
        o.x = cvtpk(v0.x, v0.y); o.y = cvtpk(v0.z, v0.w);
        o.z = cvtpk(v1.x, v1.y); o.w = cvtpk(v1.z, v1.w);
        const size_t off = (size_t)(m >> 7) * PANEL_B +
                           ((((m >> 4) & 7) * 6 + ks) * 64 + (lg << 4) + (m & 15)) * 16;
        *(uint4*)(xbf + off) = o;
    } else {
        // weight tiles: 128 unified cols x 192k, transposed + XOR-swizzled +
        // pair-interleaved (phys row p <-> logical col 2*(p&15)+((p>>4)&1)).
        const int tid = (bid - 2352) * 256 + threadIdx.x;   // 24576
        const int s = tid % 24, rem = tid / 24;
        const int p = rem & 127, tile = rem >> 7;
        const int lc = (p >> 5) * 32 + 2 * (p & 15) + ((p >> 4) & 1);
        const int u  = (tile < 6 ? tile : tile - 6) * 128 + lc;
        const float* src = nullptr; int nc = 0, col = 0;
        if (tile < 6) {
            if (u < 192)      { src = Wv; nc = 192; col = u; }
            else if (u < 678) { src = Wa; nc = NA;  col = u - 192; }
        } else {
            if (u < 192)      { src = Wp; nc = 192; col = u; }
        }
        const int k0 = s * 8;
        uint32_t d[4];
#pragma unroll
        for (int e = 0; e < 4; ++e) {
            const float f0 = src ? src[(size_t)(k0 + 2 * e) * nc + col]     : 0.f;
            const float f1 = src ? src[(size_t)(k0 + 2 * e + 1) * nc + col] : 0.f;
            d[e] = cvtpk(f0, f1);
        }
        const int sb = (s * 16) ^ ((p & 7) << 4);
        *(uint4*)(WT + (size_t)tile * TILE_B + p * 384 + sb) =
            make_uint4(d[0], d[1], d[2], d[3]);
    }
}

// =======================================================================
// 128x128 MFMA GEMM, A from frag-order global (registers, no LDS),
// B tile via 12x global_load_lds into 48KB LDS. ONE barrier per block.
// 256 thr = 4 waves (2x2); wave = 64x64 out = acc[4][4].
// OUT_DUAL: unified cols -> v (cols<192) / alog (+ba); else fp32 out (+bias).
// =======================================================================
template <bool OUT_DUAL, int NT>
__global__ __launch_bounds__(256, 2) void gemm_fr(
    const uint8_t* __restrict__ Afr,
    const uint8_t* __restrict__ WT,
    uint16_t* __restrict__ vOut, uint16_t* __restrict__ alogOut,
    const float* __restrict__ bias,
    float* __restrict__ outf) {
    __shared__ __align__(16) uint8_t sm[TILE_B];
    const int t    = threadIdx.x;
    const int wgid = xcd_swizzle(blockIdx.x, gridDim.x);
    const int mg   = wgid / NT, ti = wgid - mg * NT;
    const int m0   = mg * 128;
    const int l    = t & 63, wid = t >> 6;
    const int wr   = wid >> 1, wc = wid & 1;
    const int lr   = l & 15, lg = l >> 4;

    // ---- issue B DMA (async) ----
    const uint8_t* wt = WT + (size_t)ti * TILE_B;
#pragma unroll
    for (int i = 0; i < 12; ++i) {
        const int off = wid * 12288 + i * 1024;
        gload16(wt + off + l * 16, sm + off);
    }

    // ---- A fragments straight from global (coalesced dwordx4) ----
    const uint8_t* ap = Afr + (size_t)mg * PANEL_B;
    short8 aR[6][4];
#pragma unroll
    for (int ks = 0; ks < 6; ++ks)
#pragma unroll
        for (int mr = 0; mr < 4; ++mr) {
            const int r = wr * 4 + mr;
            aR[ks][mr] = *(const short8*)(ap + (size_t)(((r * 6 + ks) * 64) + l) * 16);
        }
    __syncthreads();       // drains B DMA (+A loads) once

    // ---- compute: 96 MFMA/wave ----
    f32x4 acc[4][4];
#pragma unroll
    for (int mr = 0; mr < 4; ++mr)
#pragma unroll
        for (int nr = 0; nr < 4; ++nr) acc[mr][nr] = f32x4{0.f, 0.f, 0.f, 0.f};
#pragma unroll
    for (int ks = 0; ks < 6; ++ks) {
        const int cb = ks * 64 + lg * 16;
        short8 b[4];
#pragma unroll
        for (int nr = 0; nr < 4; ++nr) {
            const int rn = wc * 64 + nr * 16 + lr;
            b[nr] = *(const short8*)(sm + rn * 384 + (cb ^ ((rn & 7) << 4)));
        }
#pragma unroll
        for (int mr = 0; mr < 4; ++mr)
#pragma unroll
            for (int nr = 0; nr < 4; ++nr)
                acc[mr][nr] = __builtin_amdgcn_mfma_f32_16x16x32_bf16(
                    aR[ks][mr], b[nr], acc[mr][nr], 0, 0, 0);
    }

    // ---- epilogue: frag pair (2pr,2pr+1) = adjacent memory cols ----
    const int gcol0 = ti * 128 + wc * 64;
#pragma unroll
    for (int pr = 0; pr < 2; ++pr) {
        if (OUT_DUAL) {
            const bool isv = gcol0 < 192;
            uint16_t* dst = isv ? vOut : alogOut;
            const int nc  = isv ? 192 : NA;
            const int c   = (isv ? gcol0 : gcol0 - 192) + pr * 32 + 2 * lr;
            if (c < nc) {
                const float be = isv ? 0.f : bias[c];
                const float bo = isv ? 0.f : bias[c + 1];
#pragma unroll
                for (int mr = 0; mr < 4; ++mr) {
                    const size_t rb = (size_t)(m0 + wr * 64 + mr * 16 + lg * 4);
#pragma unroll
                    for (int j = 0; j < 4; ++j)
                        *(uint32_t*)(dst + (rb + j) * nc + c) =
                            cvtpk(acc[mr][2 * pr][j] + be, acc[mr][2 * pr + 1][j] + bo);
                }
            }
        } else {
            const int c = gcol0 + pr * 32 + 2 * lr;
            if (c < 192) {
                const float be = bias[c], bo = bias[c + 1];
#pragma unroll
                for (int mr = 0; mr < 4; ++mr) {
                    const size_t rb = (size_t)(m0 + wr * 64 + mr * 16 + lg * 4);
#pragma unroll
                    for (int j = 0; j < 4; ++j)
                        *(float2*)(outf + (rb + j) * 192 + c) =
                            make_float2(acc[mr][2 * pr][j] + be,
                                        acc[mr][2 * pr + 1][j] + bo);
                }
            }
        }
    }
}

// =======================================================================
// Fused softmax + attention + fold (25-offset gather). ypre is stored in
// FRAG ORDER so the final GEMM loads A straight from global.
// =======================================================================
constexpr int TH = 4, TW = 8;
constexpr int HALO_W = TW + 4;                   // 12 (halo H = 8)
constexpr int VSTR = C + 8;                      // 200 bf16

__global__ __launch_bounds__(192) void attn_fold25(const uint16_t* __restrict__ v,
                                                   const uint16_t* __restrict__ alog,
                                                   uint8_t* __restrict__ ypre) {
    __shared__ uint16_t vl[96][VSTR];            // 38.4 KB
    const int b   = blockIdx.z;
    const int ty0 = blockIdx.y * TH, tx0 = blockIdx.x * TW;
    const int t   = threadIdx.x;

#pragma unroll
    for (int it = 0; it < 12; ++it) {
        const int f  = t + it * 192;             // 96 px * 24 slots
        const int px = f / 24, c8 = (f % 24) * 8;
        const int hy = px / HALO_W, hx = px % HALO_W;
        const int y = ty0 + hy - 2, x = tx0 + hx - 2;
        uint4 val = make_uint4(0u, 0u, 0u, 0u);
        if ((unsigned)y < HH_IMG && (unsigned)x < WW_IMG)
            val = *(const uint4*)&v[(((size_t)b * HH_IMG + y) * WW_IMG + x) * C + c8];
        *(uint4*)&vl[px][c8] = val;
    }

    const int n   = t % HEADS, pxl = t / HEADS;
    const int py  = pxl / TW, px_ = pxl % TW;
    const int Py  = ty0 + py, Px = tx0 + px_;
    const float scl2 = 0.17677669529663687f * 1.4426950408889634f;  // scale*log2e

    float cw[5][5] = {};
#pragma unroll
    for (int i = 0; i < 3; ++i)
#pragma unroll
        for (int j = 0; j < 3; ++j) {
            const int sy = Py - i + 1, sx = Px - j + 1;
            if ((unsigned)sy < HH_IMG && (unsigned)sx < WW_IMG) {
                const uint16_t* ap = alog + (((size_t)b * HH_IMG + sy) * WW_IMG + sx) * NA
                                   + n * 81 + (i * 3 + j) * 9;
                float w[9], s = 0.f;
#pragma unroll
                for (int q = 0; q < 9; ++q) {
                    w[q] = __builtin_amdgcn_exp2f(bf2f(ap[q]) * scl2);
                    s += w[q];
                }
                const float inv = __builtin_amdgcn_rcpf(s);
#pragma unroll
                for (int qi = 0; qi < 3; ++qi)
#pragma unroll
                    for (int qj = 0; qj < 3; ++qj)
                        cw[qi - i + 2][qj - j + 2] += w[qi * 3 + qj] * inv;
            }
        }
    __syncthreads();

    float acc[HD] = {};
#pragma unroll
    for (int dy = 0; dy < 5; ++dy)
#pragma unroll
        for (int dx = 0; dx < 5; ++dx) {
            const float wq = cw[dy][dx];
            const uint16_t* vp = &vl[(py + dy) * HALO_W + (px_ + dx)][n * HD];
#pragma unroll
            for (int v8 = 0; v8 < 4; ++v8) {
                const uint4 raw = *(const uint4*)&vp[v8 * 8];
                const uint32_t r0 = raw.x, r1 = raw.y, r2 = raw.z, r3 = raw.w;
                acc[v8*8+0] = fmaf(wq, bflo(r0), acc[v8*8+0]);
                acc[v8*8+1] = fmaf(wq, bfhi(r0), acc[v8*8+1]);
                acc[v8*8+2] = fmaf(wq, bflo(r1), acc[v8*8+2]);
                acc[v8*8+3] = fmaf(wq, bfhi(r1), acc[v8*8+3]);
                acc[v8*8+4] = fmaf(wq, bflo(r2), acc[v8*8+4]);
                acc[v8*8+5] = fmaf(wq, bfhi(r2), acc[v8*8+5]);
                acc[v8*8+6] = fmaf(wq, bflo(r3), acc[v8*8+6]);
                acc[v8*8+7] = fmaf(wq, bfhi(r3), acc[v8*8+7]);
            }
        }

    // ---- store ypre in FRAG ORDER: head n == ks; 4x 16B stores ----
    const int Pidx = (b * HH_IMG + Py) * WW_IMG + Px;
    uint8_t* pb = ypre + (size_t)(Pidx >> 7) * PANEL_B +
                  ((((Pidx >> 4) & 7) * 6 + n) * 64 + (Pidx & 15)) * 16;
#pragma unroll
    for (int g2 = 0; g2 < 4; ++g2) {
        uint4 o;
        o.x = cvtpk(acc[g2 * 8 + 0], acc[g2 * 8 + 1]);
        o.y = cvtpk(acc[g2 * 8 + 2], acc[g2 * 8 + 3]);
        o.z = cvtpk(acc[g2 * 8 + 4], acc[g2 * 8 + 5]);
        o.w = cvtpk(acc[g2 * 8 + 6], acc[g2 * 8 + 7]);
        *(uint4*)(pb + g2 * 256) = o;            // lg stride = 16 lanes * 16B
    }
}

// =======================================================================
extern "C" void kernel_launch(void* const* d_in, const int* in_sizes, int n_in,
                              void* d_out, int out_size, void* d_ws, size_t ws_size,
                              hipStream_t stream) {
    const float* x  = (const float*)d_in[0];
    const float* Wv = (const float*)d_in[1];
    const float* Wa = (const float*)d_in[2];
    const float* ba = (const float*)d_in[3];
    const float* Wp = (const float*)d_in[4];
    const float* bp = (const float*)d_in[5];
    float* out = (float*)d_out;

    // ws: v | alog | ypre(frag-order) | WT(8 tiles) | xbf(frag-order)
    uint16_t* v    = (uint16_t*)d_ws;
    uint16_t* alog = v + (size_t)MROWS * C;
    uint8_t*  ypre = (uint8_t*)(alog + (size_t)MROWS * NA);
    uint8_t*  WT   = ypre + (size_t)(MROWS / 128) * PANEL_B;
    uint8_t*  xbf  = WT + 8 * (size_t)TILE_B;

    // prep: x -> frag-order bf16 (2352 blocks) + weight tiles (96 blocks)
    prep_all<<<2448, 256, 0, stream>>>(x, Wv, Wa, Wp, xbf, WT);
    // fused projections: 6 tiles -> v (cols<192) + alog (+ba)
    gemm_fr<true, 6><<<(MROWS / 128) * 6, 256, 0, stream>>>(
        xbf, WT, v, alog, ba, nullptr);
    // softmax + attn + fold -> ypre (frag-order)
    attn_fold25<<<dim3(WW_IMG / TW, HH_IMG / TH, BATCH), dim3(192), 0, stream>>>(
        v, alog, ypre);
    // out = ypre @ Wp + bp (fp32)
    gemm_fr<false, 2><<<(MROWS / 128) * 2, 256, 0, stream>>>(
        ypre, WT + 6 * (size_t)TILE_B, nullptr, nullptr, bp, out);
}

// Round 7
// 60.872 us; speedup vs baseline: 1.8818x; 1.0127x over previous
//
#include <hip/hip_runtime.h>
#include <hip/hip_bf16.h>
#include <cstdint>

#define DI __device__ __forceinline__

typedef __attribute__((ext_vector_type(8))) short short8;
typedef __attribute__((ext_vector_type(4))) float f32x4;

// ---------- bf16 helpers ----------
DI float bflo(uint32_t u) { return __builtin_bit_cast(float, (uint32_t)(u << 16)); }
DI float bfhi(uint32_t u) { return __builtin_bit_cast(float, (uint32_t)(u & 0xffff0000u)); }
// HW packed cvt (RNE); no builtin on gfx950
DI uint32_t cvtpk(float lo, float hi) {
    uint32_t r;
    asm("v_cvt_pk_bf16_f32 %0, %1, %2" : "=v"(r) : "v"(lo), "v"(hi));
    return r;
}
// async global->LDS, 16B/lane (dest = wave-uniform base + lane*16)
DI void gload16(const void* g, void* s) {
    __builtin_amdgcn_global_load_lds(
        (const __attribute__((address_space(1))) uint32_t*)g,
        (__attribute__((address_space(3))) uint32_t*)s, 16, 0, 0);
}
// m204 bijective XCD-chunk swizzle
DI int xcd_swizzle(int orig, int nwg) {
    const int q = nwg >> 3, r = nwg & 7;
    const int x = orig & 7, i = orig >> 3;
    return (x < r ? x * (q + 1) : r * (q + 1) + (x - r) * q) + i;
}

// ---------- problem constants ----------
constexpr int BATCH = 8, HH_IMG = 56, WW_IMG = 56, C = 192;
constexpr int HEADS = 6, HD = 32, NA = 486;
constexpr int NAP = 528;                               // 6 heads * 88 (padded)
constexpr int MROWS = BATCH * HH_IMG * WW_IMG;         // 25088
constexpr int KK = 192;
constexpr int TILE_B  = 49152;                         // B tile: 128 cols x 384B
constexpr int PANEL_B = 49152;                         // A panel: 128 rows x 192k bf16
constexpr int WTB_B   = 73728;                         // Wp frag-order: 12 colfrag x 6 ks x 1KB

// =======================================================================
// prep_all:
//  blocks [0,2352):  x -> frag-order bf16 panels (A for proj GEMM)
//  blocks [2352,..): (a) unified weight tiles [Wv(192) | WaPadded(528)] = 720
//                        cols in 6 tiles of 128 (transposed, swizzled,
//                        pair-interleaved); pad cols (head rem 81..87) zero.
//                    (b) WTB: Wp in frag-order B layout (pair-interleaved)
//                    (c) baP[528]: padded attention bias
// =======================================================================
__global__ __launch_bounds__(256) void prep_all(const float* __restrict__ x,
                                                const float* __restrict__ Wv,
                                                const float* __restrict__ Wa,
                                                const float* __restrict__ Wp,
                                                const float* __restrict__ ba,
                                                uint8_t* __restrict__ xbf,
                                                uint8_t* __restrict__ WT,
                                                uint8_t* __restrict__ WTB,
                                                float* __restrict__ baP) {
    const int bid = blockIdx.x;
    if (bid < 2352) {
        // x[m][k0..k0+7] fp32 -> 16B bf16 granule in frag order
        const int g = bid * 256 + threadIdx.x;        // 602112 granules
        const int m = g / 24, cc = g % 24;
        const int ks = cc >> 2, lg = cc & 3;
        const float* src = x + (size_t)m * KK + cc * 8;
        const float4 v0 = *(const float4*)src;
        const float4 v1 = *(const float4*)(src + 4);
        uint4 o;
        o.x = cvtpk(v0.x, v0.y); o.y = cvtpk(v0.z, v0.w);
        o.z = cvtpk(v1.x, v1.y); o.w = cvtpk(v1.z, v1.w);
        const size_t off = (size_t)(m >> 7) * PANEL_B +
                           ((((m >> 4) & 7) * 6 + ks) * 64 + (lg << 4) + (m & 15)) * 16;
        *(uint4*)(xbf + off) = o;
        return;
    }
    const int tid = (bid - 2352) * 256 + threadIdx.x;
    if (tid < 18432) {
        // unified tiles: 6 x (128 phys cols x 24 granules)
        const int s = tid % 24, rem = tid / 24;
        const int p = rem & 127, tile = rem >> 7;
        const int lc = (p >> 5) * 32 + 2 * (p & 15) + ((p >> 4) & 1);
        const int u  = tile * 128 + lc;               // unified col 0..767
        const float* src = nullptr; int nc = 0, col = 0;
        if (u < 192) { src = Wv; nc = 192; col = u; }
        else if (u < 720) {
            const int up = u - 192;                   // padded attn col
            const int head = up / 88, r88 = up - head * 88;
            if (r88 < 81) { src = Wa; nc = NA; col = head * 81 + r88; }
        }
        const int k0 = s * 8;
        uint32_t d[4];
#pragma unroll
        for (int e = 0; e < 4; ++e) {
            const float f0 = src ? src[(size_t)(k0 + 2 * e) * nc + col]     : 0.f;
            const float f1 = src ? src[(size_t)(k0 + 2 * e + 1) * nc + col] : 0.f;
            d[e] = cvtpk(f0, f1);
        }
        const int sb = (s * 16) ^ ((p & 7) << 4);
        *(uint4*)(WT + (size_t)tile * TILE_B + p * 384 + sb) =
            make_uint4(d[0], d[1], d[2], d[3]);
    } else if (tid < 18432 + 4608) {
        // WTB: granule g = ((nrIdx*6+ks)*64 + l); col pair-interleaved
        const int g = tid - 18432;
        const int l = g & 63, gg = g >> 6;
        const int ks = gg % 6, nrIdx = gg / 6;        // nrIdx = pp*2 + h
        const int pp = nrIdx >> 1, h = nrIdx & 1;
        const int col = pp * 32 + 2 * (l & 15) + h;
        const int k0  = ks * 32 + (l >> 4) * 8;
        uint32_t d[4];
#pragma unroll
        for (int e = 0; e < 4; ++e) {
            const float f0 = Wp[(size_t)(k0 + 2 * e) * 192 + col];
            const float f1 = Wp[(size_t)(k0 + 2 * e + 1) * 192 + col];
            d[e] = cvtpk(f0, f1);
        }
        *(uint4*)(WTB + (size_t)g * 16) = make_uint4(d[0], d[1], d[2], d[3]);
    } else if (tid < 18432 + 4608 + NAP) {
        const int pc = tid - 18432 - 4608;
        const int head = pc / 88, r88 = pc - head * 88;
        baP[pc] = (r88 < 81) ? ba[head * 81 + r88] : 0.f;
    }
}

// =======================================================================
// Projection GEMM: 128x128 out tile, full K=192. A from frag-order xbf
// (registers, no LDS), B via 12x global_load_lds. ONE barrier.
// Unified cols: uc<192 -> z (bf16); 192<=uc<720 -> alogP (bf16, stride 528,
// +baP). 256 thr = 4 waves (2x2); wave = 64x64 = acc[4][4].
// =======================================================================
__global__ __launch_bounds__(256, 2) void gemm_fr(
    const uint8_t* __restrict__ Afr,
    const uint8_t* __restrict__ WT,
    uint16_t* __restrict__ zOut, uint16_t* __restrict__ alogP,
    const float* __restrict__ baP) {
    __shared__ __align__(16) uint8_t sm[TILE_B];
    const int t    = threadIdx.x;
    const int wgid = xcd_swizzle(blockIdx.x, gridDim.x);
    const int mg   = wgid / 6, ti = wgid - mg * 6;
    const int m0   = mg * 128;
    const int l    = t & 63, wid = t >> 6;
    const int wr   = wid >> 1, wc = wid & 1;
    const int lr   = l & 15, lg = l >> 4;

    // ---- issue B DMA (async) ----
    const uint8_t* wt = WT + (size_t)ti * TILE_B;
#pragma unroll
    for (int i = 0; i < 12; ++i) {
        const int off = wid * 12288 + i * 1024;
        gload16(wt + off + l * 16, sm + off);
    }

    // ---- A fragments straight from global (coalesced dwordx4) ----
    const uint8_t* ap = Afr + (size_t)mg * PANEL_B;
    short8 aR[6][4];
#pragma unroll
    for (int ks = 0; ks < 6; ++ks)
#pragma unroll
        for (int mr = 0; mr < 4; ++mr) {
            const int r = wr * 4 + mr;
            aR[ks][mr] = *(const short8*)(ap + (size_t)(((r * 6 + ks) * 64) + l) * 16);
        }
    __syncthreads();       // drains B DMA once

    // ---- compute: 96 MFMA/wave ----
    f32x4 acc[4][4];
#pragma unroll
    for (int mr = 0; mr < 4; ++mr)
#pragma unroll
        for (int nr = 0; nr < 4; ++nr) acc[mr][nr] = f32x4{0.f, 0.f, 0.f, 0.f};
#pragma unroll
    for (int ks = 0; ks < 6; ++ks) {
        const int cb = ks * 64 + lg * 16;
        short8 b[4];
#pragma unroll
        for (int nr = 0; nr < 4; ++nr) {
            const int rn = wc * 64 + nr * 16 + lr;
            b[nr] = *(const short8*)(sm + rn * 384 + (cb ^ ((rn & 7) << 4)));
        }
#pragma unroll
        for (int mr = 0; mr < 4; ++mr)
#pragma unroll
            for (int nr = 0; nr < 4; ++nr)
                acc[mr][nr] = __builtin_amdgcn_mfma_f32_16x16x32_bf16(
                    aR[ks][mr], b[nr], acc[mr][nr], 0, 0, 0);
    }

    // ---- epilogue (D col=lane&15, row=4*(lane>>4)+reg; pairs adjacent) ----
    const int gcol0 = ti * 128 + wc * 64;
#pragma unroll
    for (int pr = 0; pr < 2; ++pr) {
        const int uc = gcol0 + pr * 32 + 2 * lr;
        if (uc < 192) {
#pragma unroll
            for (int mr = 0; mr < 4; ++mr) {
                const size_t rb = (size_t)(m0 + wr * 64 + mr * 16 + lg * 4);
#pragma unroll
                for (int j = 0; j < 4; ++j)
                    *(uint32_t*)(zOut + (rb + j) * 192 + uc) =
                        cvtpk(acc[mr][2 * pr][j], acc[mr][2 * pr + 1][j]);
            }
        } else {
            const int pc = uc - 192;
            if (pc < NAP) {
                const float be = baP[pc], bo = baP[pc + 1];
#pragma unroll
                for (int mr = 0; mr < 4; ++mr) {
                    const size_t rb = (size_t)(m0 + wr * 64 + mr * 16 + lg * 4);
#pragma unroll
                    for (int j = 0; j < 4; ++j)
                        *(uint32_t*)(alogP + (rb + j) * NAP + pc) =
                            cvtpk(acc[mr][2 * pr][j] + be, acc[mr][2 * pr + 1][j] + bo);
                }
            }
        }
    }
}

// =======================================================================
// Fused softmax + fold + FINAL GEMM.
//  Phase 1: stage z halo (8x12 px) in LDS.
//  Phase 2: per (pixel,head): 9 softmaxes from padded alogP (2 uint4 loads
//           per window), accumulate 25 fold coeffs cw.
//  Phase 3: gather -> ypre[32ch] in regs; write to LDS (swizzled bf16).
//  Phase 4: out(32x192) = ypre @ Wp + bp via MFMA (3 waves x 48 MFMA),
//           B-frags from frag-order WTB (global, L2-hot). fp32 out.
// 192 threads = 32 px * 6 heads = 3 waves.
// =======================================================================
constexpr int TH = 4, TW = 8;
constexpr int HALO_W = TW + 4;                   // 12 (halo H = 8)
constexpr int VSTR = C + 8;                      // 200 bf16
constexpr int YL_OFF = 96 * VSTR * 2;            // 38400

__global__ __launch_bounds__(192) void attn_fused(const uint16_t* __restrict__ z,
                                                  const uint16_t* __restrict__ alogP,
                                                  const uint8_t* __restrict__ WTB,
                                                  const float* __restrict__ bp,
                                                  float* __restrict__ out) {
    __shared__ __align__(16) uint8_t smem[YL_OFF + 32 * 384];   // 49.5 KB
    uint16_t (*vl)[VSTR] = (uint16_t(*)[VSTR])smem;
    uint8_t* yl = smem + YL_OFF;
    const int b   = blockIdx.z;
    const int ty0 = blockIdx.y * TH, tx0 = blockIdx.x * TW;
    const int t   = threadIdx.x;

    // ---- phase 1: stage z halo ----
#pragma unroll
    for (int it = 0; it < 12; ++it) {
        const int f  = t + it * 192;
        const int px = f / 24, c8 = (f % 24) * 8;
        const int hy = px / HALO_W, hx = px % HALO_W;
        const int y = ty0 + hy - 2, x = tx0 + hx - 2;
        uint4 val = make_uint4(0u, 0u, 0u, 0u);
        if ((unsigned)y < HH_IMG && (unsigned)x < WW_IMG)
            val = *(const uint4*)&z[(((size_t)b * HH_IMG + y) * WW_IMG + x) * C + c8];
        *(uint4*)&vl[px][c8] = val;
    }

    const int n   = t % HEADS, pxl = t / HEADS;
    const int py  = pxl >> 3, px_ = pxl & 7;
    const int Py  = ty0 + py, Px = tx0 + px_;
    const float scl2 = 0.17677669529663687f * 1.4426950408889634f;  // scale*log2e

    // ---- phase 2: fold coefficients (vectorized padded-alog reads) ----
    float cw[5][5] = {};
#pragma unroll
    for (int i = 0; i < 3; ++i)
#pragma unroll
        for (int j = 0; j < 3; ++j) {
            const int sy = Py - i + 1, sx = Px - j + 1;
            if ((unsigned)sy < HH_IMG && (unsigned)sx < WW_IMG) {
                const uint8_t* rp = (const uint8_t*)alogP +
                    (((size_t)b * HH_IMG + sy) * WW_IMG + sx) * (NAP * 2) + n * 176;
                const int win = i * 3 + j;
                const int off = win * 18, a0 = off & ~15, base = off - a0;
                const uint4 u0 = *(const uint4*)(rp + a0);
                const uint4 u1 = *(const uint4*)(rp + a0 + 16);
                const uint32_t dd[8] = {u0.x, u0.y, u0.z, u0.w, u1.x, u1.y, u1.z, u1.w};
                float w[9], s = 0.f;
#pragma unroll
                for (int q = 0; q < 9; ++q) {
                    const int bb = base + 2 * q;
                    const uint32_t dw = dd[bb >> 2];
                    const float f0 = (bb & 2) ? bfhi(dw) : bflo(dw);
                    w[q] = __builtin_amdgcn_exp2f(f0 * scl2);
                    s += w[q];
                }
                const float inv = __builtin_amdgcn_rcpf(s);
#pragma unroll
                for (int qi = 0; qi < 3; ++qi)
#pragma unroll
                    for (int qj = 0; qj < 3; ++qj)
                        cw[qi - i + 2][qj - j + 2] += w[qi * 3 + qj] * inv;
            }
        }
    __syncthreads();

    // ---- phase 3: 25-offset gather ----
    float acc[HD] = {};
#pragma unroll
    for (int dy = 0; dy < 5; ++dy)
#pragma unroll
        for (int dx = 0; dx < 5; ++dx) {
            const float wq = cw[dy][dx];
            const uint16_t* vp = &vl[(py + dy) * HALO_W + (px_ + dx)][n * HD];
#pragma unroll
            for (int v8 = 0; v8 < 4; ++v8) {
                const uint4 raw = *(const uint4*)&vp[v8 * 8];
                const uint32_t r0 = raw.x, r1 = raw.y, r2 = raw.z, r3 = raw.w;
                acc[v8*8+0] = fmaf(wq, bflo(r0), acc[v8*8+0]);
                acc[v8*8+1] = fmaf(wq, bfhi(r0), acc[v8*8+1]);
                acc[v8*8+2] = fmaf(wq, bflo(r1), acc[v8*8+2]);
                acc[v8*8+3] = fmaf(wq, bfhi(r1), acc[v8*8+3]);
                acc[v8*8+4] = fmaf(wq, bflo(r2), acc[v8*8+4]);
                acc[v8*8+5] = fmaf(wq, bfhi(r2), acc[v8*8+5]);
                acc[v8*8+6] = fmaf(wq, bflo(r3), acc[v8*8+6]);
                acc[v8*8+7] = fmaf(wq, bfhi(r3), acc[v8*8+7]);
            }
        }

    // ---- ypre -> LDS (bf16, XOR-swizzled rows of 384B) ----
    {
        uint8_t* pb = yl + pxl * 384;
        const int key = (pxl & 7) << 4;
#pragma unroll
        for (int g2 = 0; g2 < 4; ++g2) {
            uint4 o;
            o.x = cvtpk(acc[g2 * 8 + 0], acc[g2 * 8 + 1]);
            o.y = cvtpk(acc[g2 * 8 + 2], acc[g2 * 8 + 3]);
            o.z = cvtpk(acc[g2 * 8 + 4], acc[g2 * 8 + 5]);
            o.w = cvtpk(acc[g2 * 8 + 6], acc[g2 * 8 + 7]);
            *(uint4*)(pb + ((n * 64 + g2 * 16) ^ key)) = o;
        }
    }
    __syncthreads();

    // ---- phase 4: out = ypre @ Wp + bp (3 waves, wave = 32x64 cols) ----
    const int l = t & 63, wid = t >> 6;
    const int lr = l & 15, lg = l >> 4;
    short8 aF[2][6];
#pragma unroll
    for (int r = 0; r < 2; ++r)
#pragma unroll
        for (int ks = 0; ks < 6; ++ks) {
            const int row = r * 16 + lr;
            aF[r][ks] = *(const short8*)(yl + row * 384 +
                          ((ks * 64 + lg * 16) ^ ((row & 7) << 4)));
        }
    f32x4 gacc[2][4];
#pragma unroll
    for (int r = 0; r < 2; ++r)
#pragma unroll
        for (int f = 0; f < 4; ++f) gacc[r][f] = f32x4{0.f, 0.f, 0.f, 0.f};
#pragma unroll
    for (int ks = 0; ks < 6; ++ks) {
        short8 bF[4];
#pragma unroll
        for (int f = 0; f < 4; ++f) {
            const int nrIdx = wid * 4 + f;
            bF[f] = *(const short8*)(WTB + (size_t)(((nrIdx * 6 + ks) * 64) + l) * 16);
        }
#pragma unroll
        for (int r = 0; r < 2; ++r)
#pragma unroll
            for (int f = 0; f < 4; ++f)
                gacc[r][f] = __builtin_amdgcn_mfma_f32_16x16x32_bf16(
                    aF[r][ks], bF[f], gacc[r][f], 0, 0, 0);
    }

    // ---- epilogue: fp32 out, pairs adjacent via pair-interleaved WTB ----
#pragma unroll
    for (int pi = 0; pi < 2; ++pi) {
        const int col = wid * 64 + pi * 32 + 2 * lr;
        const float be = bp[col], bo = bp[col + 1];
#pragma unroll
        for (int r = 0; r < 2; ++r)
#pragma unroll
            for (int j = 0; j < 4; ++j) {
                const int prow = r * 16 + lg * 4 + j;
                const int gy = ty0 + (prow >> 3), gx = tx0 + (prow & 7);
                float* op = out + (((size_t)b * HH_IMG + gy) * WW_IMG + gx) * C + col;
                *(float2*)op = make_float2(gacc[r][2 * pi][j] + be,
                                           gacc[r][2 * pi + 1][j] + bo);
            }
    }
}

// =======================================================================
extern "C" void kernel_launch(void* const* d_in, const int* in_sizes, int n_in,
                              void* d_out, int out_size, void* d_ws, size_t ws_size,
                              hipStream_t stream) {
    const float* x  = (const float*)d_in[0];
    const float* Wv = (const float*)d_in[1];
    const float* Wa = (const float*)d_in[2];
    const float* ba = (const float*)d_in[3];
    const float* Wp = (const float*)d_in[4];
    const float* bp = (const float*)d_in[5];
    float* out = (float*)d_out;

    // ws: z | alogP | xbf | WT | WTB | baP
    uint16_t* z     = (uint16_t*)d_ws;
    uint16_t* alogP = z + (size_t)MROWS * C;
    uint8_t*  xbf   = (uint8_t*)(alogP + (size_t)MROWS * NAP);
    uint8_t*  WT    = xbf + (size_t)(MROWS / 128) * PANEL_B;
    uint8_t*  WTB   = WT + 6 * (size_t)TILE_B;
    float*    baP   = (float*)(WTB + WTB_B);

    // prep: x->frag-order (2352 blocks) + tiles/WTB/baP (93 blocks)
    prep_all<<<2352 + 93, 256, 0, stream>>>(x, Wv, Wa, Wp, ba, xbf, WT, WTB, baP);
    // projections: 6 unified tiles -> z (uc<192) + alogP (padded, +baP)
    gemm_fr<<<(MROWS / 128) * 6, 256, 0, stream>>>(xbf, WT, z, alogP, baP);
    // softmax + fold + final GEMM -> out
    attn_fused<<<dim3(WW_IMG / TW, HH_IMG / TH, BATCH), dim3(192), 0, stream>>>(
        z, alogP, WTB, bp, out);
}